// Round 1
// baseline (134.666 us; speedup 1.0000x reference)
//
#include <hip/hip_runtime.h>

typedef __bf16 bf16_t;
typedef __bf16 bf16x8 __attribute__((ext_vector_type(8)));
typedef __bf16 bf16x4 __attribute__((ext_vector_type(4)));
typedef float f32x4 __attribute__((ext_vector_type(4)));

__device__ __forceinline__ void async16(const void* g, void* l) {
  __builtin_amdgcn_global_load_lds(
      (const __attribute__((address_space(1))) unsigned int*)g,
      (__attribute__((address_space(3))) unsigned int*)l,
      16, 0, 0);
}

// ---------------------------------------------------------------------------
// float -> bf16 straight conversion, float4-vectorized (n4 = elements/4)
// ---------------------------------------------------------------------------
__global__ void convert_f32_bf16(const float* __restrict__ in,
                                 bf16_t* __restrict__ out, int n4) {
  int i = blockIdx.x * blockDim.x + threadIdx.x;
  if (i >= n4) return;
  float4 v = ((const float4*)in)[i];
  bf16x4 o;
  o[0] = (bf16_t)v.x; o[1] = (bf16_t)v.y; o[2] = (bf16_t)v.z; o[3] = (bf16_t)v.w;
  ((bf16x4*)out)[i] = o;
}

// ---------------------------------------------------------------------------
// proj_L (1024x256 f32, row-major) -> out (256x1024 bf16) = L^T
// LDS-tiled transpose, 32x32 tiles, block (32,8)
// ---------------------------------------------------------------------------
__global__ void transpose_L(const float* __restrict__ in,
                            bf16_t* __restrict__ out) {
  __shared__ float tile[32][33];
  const int n0 = blockIdx.x * 32;  // col block in input (N)
  const int k0 = blockIdx.y * 32;  // row block in input (K)
  const int tx = threadIdx.x;      // 0..31
  const int ty = threadIdx.y;      // 0..7
#pragma unroll
  for (int i = 0; i < 32; i += 8)
    tile[ty + i][tx] = in[(long)(k0 + ty + i) * 256 + n0 + tx];
  __syncthreads();
#pragma unroll
  for (int i = 0; i < 32; i += 8)
    out[(long)(n0 + ty + i) * 1024 + k0 + tx] = (bf16_t)tile[tx][ty + i];
}

// ---------------------------------------------------------------------------
// C(MxN) = A(MxK, lda) @ Bt(NxK, ldb)^T   -- both operands K-contiguous
// 128x128 block tile, 256 threads (4 waves, 2x2), 4x4 16x16x32 MFMA per wave
// BK=32, single LDS buffer, global_load_lds width-16 staging (m97 structure)
// ---------------------------------------------------------------------------
template <bool BF16_OUT>
__global__ __launch_bounds__(256) void gemm_bt(
    const bf16_t* __restrict__ A0, long sA, int lda,
    const bf16_t* __restrict__ B0, long sB, int ldb,
    void* __restrict__ C0, long sC, int ldc,
    int K, int tilesN, const float* __restrict__ bias) {
  const int bz = blockIdx.y;
  const bf16_t* A = A0 + (long)bz * sA;
  const bf16_t* Bt = B0 + (long)bz * sB;
  const int tm = (int)(blockIdx.x / tilesN) * 128;
  const int tn = (int)(blockIdx.x % tilesN) * 128;

  __shared__ __attribute__((aligned(16))) bf16_t As[128 * 32];
  __shared__ __attribute__((aligned(16))) bf16_t Bs[128 * 32];

  const int t = threadIdx.x;
  const int lane = t & 63;
  const int quad = lane >> 4;   // 0..3
  const int l15 = lane & 15;
  const int wave = t >> 6;      // 0..3
  const int wr = (wave >> 1) * 64;  // wave row offset in tile
  const int wc = (wave & 1) * 64;   // wave col offset in tile

  // staging: thread t loads 16B chunks; chunk c covers rows c*64 + t/4,
  // cols (t%4)*8 .. +7  -> LDS flat offset c*2048 + t*8 elements
  const int rS = t >> 2;
  const int cS = (t & 3) * 8;
  const bf16_t* gA = A + (long)(tm + rS) * lda + cS;
  const bf16_t* gB = Bt + (long)(tn + rS) * ldb + cS;
  bf16_t* lA = As + t * 8;
  bf16_t* lB = Bs + t * 8;

  f32x4 acc[4][4];
#pragma unroll
  for (int i = 0; i < 4; ++i)
#pragma unroll
    for (int j = 0; j < 4; ++j)
      acc[i][j] = (f32x4){0.f, 0.f, 0.f, 0.f};

  for (int k0 = 0; k0 < K; k0 += 32) {
    async16(gA + k0, lA);
    async16(gA + k0 + (long)64 * lda, lA + 2048);
    async16(gB + k0, lB);
    async16(gB + k0 + (long)64 * ldb, lB + 2048);
    __syncthreads();  // drains vmcnt -> LDS tiles valid

    bf16x8 af[4], bv[4];
#pragma unroll
    for (int i = 0; i < 4; ++i)
      af[i] = *(const bf16x8*)(As + (wr + i * 16 + l15) * 32 + quad * 8);
#pragma unroll
    for (int j = 0; j < 4; ++j)
      bv[j] = *(const bf16x8*)(Bs + (wc + j * 16 + l15) * 32 + quad * 8);
#pragma unroll
    for (int i = 0; i < 4; ++i)
#pragma unroll
      for (int j = 0; j < 4; ++j)
        acc[i][j] = __builtin_amdgcn_mfma_f32_16x16x32_bf16(af[i], bv[j],
                                                            acc[i][j], 0, 0, 0);
    __syncthreads();  // all waves done reading LDS before next overwrite
  }

  // Epilogue. C/D layout (verified m89/m91): col = lane&15, row = quad*4 + reg
  if constexpr (BF16_OUT) {
    bf16_t* C = (bf16_t*)C0 + (long)bz * sC;
#pragma unroll
    for (int i = 0; i < 4; ++i) {
      const int r0 = tm + wr + i * 16 + quad * 4;
#pragma unroll
      for (int j = 0; j < 4; ++j) {
        const int c0 = tn + wc + j * 16 + l15;
#pragma unroll
        for (int r = 0; r < 4; ++r)
          C[(long)(r0 + r) * ldc + c0] = (bf16_t)acc[i][j][r];
      }
    }
  } else {
    float* C = (float*)C0 + (long)bz * sC;
    const float bvadd = bias[0];
#pragma unroll
    for (int i = 0; i < 4; ++i) {
      const int r0 = tm + wr + i * 16 + quad * 4;
#pragma unroll
      for (int j = 0; j < 4; ++j) {
        const int c0 = tn + wc + j * 16 + l15;
#pragma unroll
        for (int r = 0; r < 4; ++r)
          C[(long)(r0 + r) * ldc + c0] = acc[i][j][r] + bvadd;
      }
    }
  }
}

extern "C" void kernel_launch(void* const* d_in, const int* in_sizes, int n_in,
                              void* d_out, int out_size, void* d_ws,
                              size_t ws_size, hipStream_t stream) {
  const float* batch = (const float*)d_in[0];  // (8,1024,1024)
  const float* projL = (const float*)d_in[1];  // (1024,256)
  const float* projR = (const float*)d_in[2];  // (256,1024)
  const float* bias = (const float*)d_in[3];   // (1,)
  float* out = (float*)d_out;                  // (8,1024,1024)

  constexpr int B = 8, S = 1024, D = 1024, R = 256;
  constexpr long nBatch = (long)B * S * D;  // 8388608

  // workspace layout (26.2 MB total)
  char* ws = (char*)d_ws;
  bf16_t* batch_bf = (bf16_t*)ws;                              // 16.78 MB
  bf16_t* Bcat = (bf16_t*)(ws + nBatch * 2);                   // 512x1024 bf16
  bf16_t* LR = (bf16_t*)(ws + nBatch * 2 + (long)512 * 1024 * 2);  // 8192x512 bf16

  // 1) batch -> bf16
  convert_f32_bf16<<<(int)(nBatch / 4 + 255) / 256, 256, 0, stream>>>(
      batch, batch_bf, (int)(nBatch / 4));
  // 2) proj_R -> bf16 into Bcat rows 256..511 (already N x K layout)
  convert_f32_bf16<<<(R * D / 4 + 255) / 256, 256, 0, stream>>>(
      projR, Bcat + (long)256 * 1024, R * D / 4);
  // 3) proj_L^T -> bf16 into Bcat rows 0..255
  transpose_L<<<dim3(8, 32), dim3(32, 8), 0, stream>>>(projL, Bcat);

  // 4) GEMM1: LR(8192x512) = batch_bf(8192x1024) @ Bcat(512x1024)^T, bf16 out
  gemm_bt<true><<<dim3(64 * 4, 1), 256, 0, stream>>>(
      batch_bf, 0L, D, Bcat, 0L, D, (void*)LR, 0L, 512, D, 4, nullptr);

  // 5) GEMM2: out[b](1024x1024) = left[b](1024x256) @ right[b](1024x256)^T + bias
  //    left  = LR[b] cols   0..255 (ld=512)
  //    right = LR[b] cols 256..511 (ld=512)
  gemm_bt<false><<<dim3(8 * 8, 8), 256, 0, stream>>>(
      LR, (long)S * 512, 512, LR + 256, (long)S * 512, 512, (void*)out,
      (long)S * S, S, R, 8, bias);
}

// Round 2
// 122.974 us; speedup vs baseline: 1.0951x; 1.0951x over previous
//
#include <hip/hip_runtime.h>

typedef __bf16 bf16_t;
typedef __bf16 bf16x8 __attribute__((ext_vector_type(8)));
typedef __bf16 bf16x4 __attribute__((ext_vector_type(4)));
typedef float f32x4 __attribute__((ext_vector_type(4)));

__device__ __forceinline__ void async16(const void* g, void* l) {
  __builtin_amdgcn_global_load_lds(
      (const __attribute__((address_space(1))) unsigned int*)g,
      (__attribute__((address_space(3))) unsigned int*)l,
      16, 0, 0);
}

// ---------------------------------------------------------------------------
// float -> bf16 straight conversion, float4-vectorized (n4 = elements/4)
// ---------------------------------------------------------------------------
__global__ void convert_f32_bf16(const float* __restrict__ in,
                                 bf16_t* __restrict__ out, int n4) {
  int i = blockIdx.x * blockDim.x + threadIdx.x;
  if (i >= n4) return;
  float4 v = ((const float4*)in)[i];
  bf16x4 o;
  o[0] = (bf16_t)v.x; o[1] = (bf16_t)v.y; o[2] = (bf16_t)v.z; o[3] = (bf16_t)v.w;
  ((bf16x4*)out)[i] = o;
}

// ---------------------------------------------------------------------------
// Fused prep for Bcat (512 x 1024 bf16):
//   blocks 0..255   : straight convert proj_R (256x1024 f32) -> Bcat rows 256..511
//   blocks 256..511 : LDS-tiled transpose proj_L (1024x256 f32) -> Bcat rows 0..255
// block = 256 threads flat
// ---------------------------------------------------------------------------
__global__ void prep_Bcat(const float* __restrict__ projL,
                          const float* __restrict__ projR,
                          bf16_t* __restrict__ Bcat) {
  const int t = threadIdx.x;
  if (blockIdx.x < 256) {
    // convert proj_R: 256*1024 = 262144 floats = 65536 float4; 256 blocks*256 thr
    int i = blockIdx.x * 256 + t;
    float4 v = ((const float4*)projR)[i];
    bf16x4 o;
    o[0] = (bf16_t)v.x; o[1] = (bf16_t)v.y; o[2] = (bf16_t)v.z; o[3] = (bf16_t)v.w;
    ((bf16x4*)(Bcat + (long)256 * 1024))[i] = o;
  } else {
    // transpose proj_L in 32x32 tiles: 8 col-tiles x 32 row-tiles = 256 blocks
    __shared__ float tile[32][33];
    const int bb = blockIdx.x - 256;
    const int n0 = (bb & 7) * 32;   // col block in projL (N=256)
    const int k0 = (bb >> 3) * 32;  // row block in projL (K=1024)
    const int tx = t & 31;
    const int ty = t >> 5;  // 0..7
#pragma unroll
    for (int i = 0; i < 32; i += 8)
      tile[ty + i][tx] = projL[(long)(k0 + ty + i) * 256 + n0 + tx];
    __syncthreads();
#pragma unroll
    for (int i = 0; i < 32; i += 8)
      Bcat[(long)(n0 + ty + i) * 1024 + k0 + tx] = (bf16_t)tile[tx][ty + i];
  }
}

// ---------------------------------------------------------------------------
// C(MxN) = A(MxK, lda) @ Bt(NxK, ldb)^T   -- both operands K-contiguous
// 128x128 block tile, 256 threads (4 waves, 2x2), 4x4 16x16x32 MFMA per wave.
// Effective BK=128 per barrier as 4 independent BK=32 sub-tiles (keeps the
// proven m97 64B-row-stride LDS layout; avoids wide-row bank conflicts).
// LDS = 64 KB -> 1-2 blocks/CU, which matches the grid-limited occupancy.
// K must be a multiple of 128.
// ---------------------------------------------------------------------------
template <bool BF16_OUT>
__global__ __launch_bounds__(256) void gemm_bt(
    const bf16_t* __restrict__ A0, long sA, int lda,
    const bf16_t* __restrict__ B0, long sB, int ldb,
    void* __restrict__ C0, long sC, int ldc,
    int K, int tilesN, const float* __restrict__ bias) {
  const int bz = blockIdx.y;
  const bf16_t* A = A0 + (long)bz * sA;
  const bf16_t* Bt = B0 + (long)bz * sB;
  const int tm = (int)(blockIdx.x / tilesN) * 128;
  const int tn = (int)(blockIdx.x % tilesN) * 128;

  // 4 sub-tiles of 128x32 bf16 each (8 KB each): 32 KB per matrix
  __shared__ __attribute__((aligned(16))) bf16_t As[4 * 128 * 32];
  __shared__ __attribute__((aligned(16))) bf16_t Bs[4 * 128 * 32];

  const int t = threadIdx.x;
  const int lane = t & 63;
  const int quad = lane >> 4;   // 0..3
  const int l15 = lane & 15;
  const int wave = t >> 6;      // 0..3
  const int wr = (wave >> 1) * 64;  // wave row offset in tile
  const int wc = (wave & 1) * 64;   // wave col offset in tile

  // staging (per sub-tile, identical to m97 layout): thread t loads 16B chunks;
  // chunk c covers row c*64 + t/4, cols (t%4)*8..+7 -> LDS flat t*8 + c*2048
  const int rS = t >> 2;
  const int cS = (t & 3) * 8;
  const bf16_t* gA = A + (long)(tm + rS) * lda + cS;
  const bf16_t* gB = Bt + (long)(tn + rS) * ldb + cS;
  bf16_t* lA = As + t * 8;
  bf16_t* lB = Bs + t * 8;

  f32x4 acc[4][4];
#pragma unroll
  for (int i = 0; i < 4; ++i)
#pragma unroll
    for (int j = 0; j < 4; ++j)
      acc[i][j] = (f32x4){0.f, 0.f, 0.f, 0.f};

  for (int k0 = 0; k0 < K; k0 += 128) {
#pragma unroll
    for (int kc = 0; kc < 4; ++kc) {
      const int ko = k0 + kc * 32;
      const int lo = kc * 4096;  // elements
      async16(gA + ko, lA + lo);
      async16(gA + ko + (long)64 * lda, lA + lo + 2048);
      async16(gB + ko, lB + lo);
      async16(gB + ko + (long)64 * ldb, lB + lo + 2048);
    }
    __syncthreads();  // drains vmcnt -> all 4 sub-tiles valid

#pragma unroll
    for (int kc = 0; kc < 4; ++kc) {
      const bf16_t* Ak = As + kc * 4096;
      const bf16_t* Bk = Bs + kc * 4096;
      bf16x8 af[4], bv[4];
#pragma unroll
      for (int i = 0; i < 4; ++i)
        af[i] = *(const bf16x8*)(Ak + (wr + i * 16 + l15) * 32 + quad * 8);
#pragma unroll
      for (int j = 0; j < 4; ++j)
        bv[j] = *(const bf16x8*)(Bk + (wc + j * 16 + l15) * 32 + quad * 8);
#pragma unroll
      for (int i = 0; i < 4; ++i)
#pragma unroll
        for (int j = 0; j < 4; ++j)
          acc[i][j] = __builtin_amdgcn_mfma_f32_16x16x32_bf16(af[i], bv[j],
                                                              acc[i][j], 0, 0, 0);
    }
    __syncthreads();  // all waves done reading LDS before next overwrite
  }

  // Epilogue. C/D layout (verified m89/m91): col = lane&15, row = quad*4 + reg
  if constexpr (BF16_OUT) {
    bf16_t* C = (bf16_t*)C0 + (long)bz * sC;
#pragma unroll
    for (int i = 0; i < 4; ++i) {
      const int r0 = tm + wr + i * 16 + quad * 4;
#pragma unroll
      for (int j = 0; j < 4; ++j) {
        const int c0 = tn + wc + j * 16 + l15;
#pragma unroll
        for (int r = 0; r < 4; ++r)
          C[(long)(r0 + r) * ldc + c0] = (bf16_t)acc[i][j][r];
      }
    }
  } else {
    float* C = (float*)C0 + (long)bz * sC;
    const float bvadd = bias[0];
#pragma unroll
    for (int i = 0; i < 4; ++i) {
      const int r0 = tm + wr + i * 16 + quad * 4;
#pragma unroll
      for (int j = 0; j < 4; ++j) {
        const int c0 = tn + wc + j * 16 + l15;
#pragma unroll
        for (int r = 0; r < 4; ++r)
          C[(long)(r0 + r) * ldc + c0] = acc[i][j][r] + bvadd;
      }
    }
  }
}

extern "C" void kernel_launch(void* const* d_in, const int* in_sizes, int n_in,
                              void* d_out, int out_size, void* d_ws,
                              size_t ws_size, hipStream_t stream) {
  const float* batch = (const float*)d_in[0];  // (8,1024,1024)
  const float* projL = (const float*)d_in[1];  // (1024,256)
  const float* projR = (const float*)d_in[2];  // (256,1024)
  const float* bias = (const float*)d_in[3];   // (1,)
  float* out = (float*)d_out;                  // (8,1024,1024)

  constexpr int B = 8, S = 1024, D = 1024, R = 256;
  constexpr long nBatch = (long)B * S * D;  // 8388608

  // workspace layout (26.2 MB total)
  char* ws = (char*)d_ws;
  bf16_t* batch_bf = (bf16_t*)ws;                                  // 16.78 MB
  bf16_t* Bcat = (bf16_t*)(ws + nBatch * 2);                       // 512x1024
  bf16_t* LR = (bf16_t*)(ws + nBatch * 2 + (long)512 * 1024 * 2);  // 8192x512

  // 1) batch -> bf16
  convert_f32_bf16<<<(int)(nBatch / 4 + 255) / 256, 256, 0, stream>>>(
      batch, batch_bf, (int)(nBatch / 4));
  // 2) Bcat: rows 0..255 = proj_L^T, rows 256..511 = proj_R (both bf16)
  prep_Bcat<<<512, 256, 0, stream>>>(projL, projR, Bcat);

  // 3) GEMM1: LR(8192x512) = batch_bf(8192x1024) @ Bcat(512x1024)^T, bf16 out
  //    grid 256 blocks (1/CU) -> BK=128 amortizes the vmcnt-drain barriers
  gemm_bt<true><<<dim3(64 * 4, 1), 256, 0, stream>>>(
      batch_bf, 0L, D, Bcat, 0L, D, (void*)LR, 0L, 512, D, 4, nullptr);

  // 4) GEMM2: out[b](1024x1024) = left[b](1024x256) @ right[b](1024x256)^T + bias
  //    left  = LR[b] cols   0..255 (ld=512); right = LR[b] cols 256..511
  //    K=256 -> just 2 barrier iterations at BK=128
  gemm_bt<false><<<dim3(8 * 8, 8), 256, 0, stream>>>(
      LR, (long)S * 512, 512, LR + 256, (long)S * 512, 512, (void*)out,
      (long)S * S, S, R, 8, bias);
}